// Round 23
// baseline (165.954 us; speedup 1.0000x reference)
//
#include <hip/hip_runtime.h>
#include <hip/hip_bf16.h>
#include <stdint.h>

// Problem constants
#define B_  4
#define T_  2048
#define C_  1024
#define H_  16
#define D_  64
#define BT  (B_*T_)     // 8192
#define KDIM 1024

typedef __attribute__((ext_vector_type(8))) short bf16x8;
typedef __attribute__((ext_vector_type(4))) float f32x4;

__device__ __forceinline__ unsigned short f2bf(float f) {
  union { float f; unsigned u; } v; v.f = f;
  unsigned r = v.u + 0x7FFFu + ((v.u >> 16) & 1u);   // RNE
  return (unsigned short)(r >> 16);
}

__device__ __forceinline__ float exp2_fast(float x) {   // raw v_exp_f32 (2^x)
  float r;
  asm("v_exp_f32 %0, %1" : "=v"(r) : "v"(x));
  return r;
}

// async global->LDS, 16B per lane. dest must be wave-uniform base + lane*16 (linear).
__device__ __forceinline__ void gld_lds16(const void* g, void* l) {
  __builtin_amdgcn_global_load_lds(
      (__attribute__((address_space(1))) unsigned int*)(uintptr_t)g,
      (__attribute__((address_space(3))) unsigned int*)(unsigned)(uintptr_t)l,
      16, 0, 0);
}

// ---------------------------------------------------------------- prep kernels
__global__ __launch_bounds__(256) void k_convert(
    const float* __restrict__ x,  const float* __restrict__ wq,
    const float* __restrict__ wk, const float* __restrict__ wv,
    const float* __restrict__ wp,
    unsigned short* __restrict__ xb, unsigned short* __restrict__ wcat,
    unsigned short* __restrict__ wpb)
{
  const int NX = BT*C_/4;       // 2097152 float4s of x
  const int NW = C_*C_/4;       // 262144 per W
  const int TOT = NX + 4*NW;
  for (int i = blockIdx.x*blockDim.x + threadIdx.x; i < TOT; i += gridDim.x*blockDim.x) {
    const float4* src; unsigned short* dst; int idx;
    if (i < NX)                { src = (const float4*)x;  dst = xb;            idx = i; }
    else {
      int j = i - NX;
      if (j < NW)              { src = (const float4*)wq; dst = wcat;          idx = j; }
      else if (j < 2*NW)       { src = (const float4*)wk; dst = wcat + C_*C_;  idx = j - NW; }
      else if (j < 3*NW)       { src = (const float4*)wv; dst = wcat + 2*C_*C_;idx = j - 2*NW; }
      else                     { src = (const float4*)wp; dst = wpb;           idx = j - 3*NW; }
    }
    float4 v = src[idx];
    ushort4 o; o.x = f2bf(v.x); o.y = f2bf(v.y); o.z = f2bf(v.z); o.w = f2bf(v.w);
    *(ushort4*)(dst + (size_t)idx*4) = o;
  }
}

// RoPE tables [T][D] (coalesced epilogue loads).
__global__ __launch_bounds__(256) void k_rope_tab(
    const int* __restrict__ start_pos, float* __restrict__ cosT, float* __restrict__ sinT)
{
  int i = blockIdx.x*blockDim.x + threadIdx.x;   // [0, T_*64)
  if (i >= T_*D_) return;
  int t = i >> 6, j = i & 63;
  float inv = exp2f(-(float)(j & 31) * (13.287712379549449f / 32.0f));
  float ang = (float)(t + start_pos[0]) * inv;
  cosT[i] = cosf(ang);
  sinT[i] = sinf(ang);
}

// ---------------------------------------------------------------- 256x192 16-wave GEMM (QKV + RoPE)
// (unchanged from R20-R22 passing kernel)
__global__ __launch_bounds__(1024, 4) void k_gemm256(
    const unsigned short* __restrict__ A, const unsigned short* __restrict__ Bw,
    unsigned short* __restrict__ qb, unsigned short* __restrict__ kb,
    unsigned short* __restrict__ vt,
    const float* __restrict__ cosT, const float* __restrict__ sinT)
{
  __shared__ __attribute__((aligned(16))) char smem[114688];   // 2 x 57344
  const int tid = threadIdx.x, l = tid & 63, w = tid >> 6;     // w in 0..15
  const int g = l >> 4, c = l & 15;
  const int m0 = blockIdx.x * 256, n0 = blockIdx.y * 192;
  const int wr = w >> 2, wc = w & 3;
  const char* gA = (const char*)A;
  const char* gB = (const char*)Bw;

  int dstA[2]; size_t aoff[2];
#pragma unroll
  for (int j = 0; j < 2; ++j) {
    int P = j*16384 + tid*16;
    int row = P >> 7;                        // 0..255
    int kc = ((P & 127) ^ ((row & 7) << 4)) >> 1;
    dstA[j] = P;
    aoff[j] = ((size_t)(m0 + row) * KDIM + kc) * 2;
  }
  int dstB[2]; size_t boff[2];
#pragma unroll
  for (int j = 0; j < 2; ++j) {
    int P = (j == 0) ? tid*16 : (16384 + tid*16);   // j=1 valid only tid<512
    int row = P >> 7;
    int kc = ((P & 127) ^ ((row & 7) << 4)) >> 1;
    dstB[j] = P;
    boff[j] = ((size_t)(n0 + row) * KDIM + kc) * 2;
  }
  const bool bsec = (tid < 512);

  const int aB = (wr*64 + c) * 128;            // + par + mi*2048 + xt
  const int bB = 32768 + (wc*48 + c) * 128;    // + par + ni*2048 + xt
  const int xsw = (c & 7) << 4;

  f32x4 acc[4][3];
#pragma unroll
  for (int i = 0; i < 4; ++i)
#pragma unroll
    for (int j = 0; j < 3; ++j) acc[i][j] = (f32x4){0.f,0.f,0.f,0.f};

#pragma unroll
  for (int j = 0; j < 2; ++j) gld_lds16(gA + aoff[j], smem + dstA[j]);
  gld_lds16(gB + boff[0], smem + 32768 + dstB[0]);
  if (bsec) gld_lds16(gB + boff[1], smem + 32768 + dstB[1]);

  for (int t = 0; t < 16; ++t) {
    const int par = (t & 1) ? 57344 : 0;
    const int nxt = (t & 1) ? 0 : 57344;

    __syncthreads();

    if (t + 1 < 16) {
      const size_t ko = (size_t)(t + 1) * 128;
#pragma unroll
      for (int j = 0; j < 2; ++j) gld_lds16(gA + aoff[j] + ko, smem + nxt + dstA[j]);
      gld_lds16(gB + boff[0] + ko, smem + nxt + 32768 + dstB[0]);
      if (bsec) gld_lds16(gB + boff[1] + ko, smem + nxt + 32768 + dstB[1]);
    }

#pragma unroll
    for (int kk = 0; kk < 2; ++kk) {
      const int xt = (kk*64 + g*16) ^ xsw;
      bf16x8 af[4], bk[3];
#pragma unroll
      for (int ni = 0; ni < 3; ++ni)
        bk[ni] = *(const bf16x8*)(smem + par + bB + ni*2048 + xt);
#pragma unroll
      for (int mi = 0; mi < 4; ++mi)
        af[mi] = *(const bf16x8*)(smem + par + aB + mi*2048 + xt);
      __builtin_amdgcn_s_setprio(1);
#pragma unroll
      for (int mi = 0; mi < 4; ++mi)
#pragma unroll
        for (int ni = 0; ni < 3; ++ni)
          acc[mi][ni] = __builtin_amdgcn_mfma_f32_16x16x32_bf16(af[mi], bk[ni], acc[mi][ni], 0, 0, 0);
      __builtin_amdgcn_s_setprio(0);
    }
  }

  // epilogue: fused RoPE; C layout: col = lane&15, row = g*4 + r
#pragma unroll
  for (int mi = 0; mi < 4; ++mi) {
#pragma unroll
    for (int ni = 0; ni < 3; ++ni) {
      const int mrow0 = m0 + wr*64 + mi*16 + g*4;
      const int ncol  = n0 + wc*48 + ni*16 + c;
      const int which = ncol >> 10;          // 0=q 1=k 2=v
      const int d = ncol & 1023, h = d >> 6, dd = d & 63;
      const int b = mrow0 >> 11, t0 = mrow0 & 2047;
      if (which == 2) {
        ushort4 o;
        o.x = f2bf(acc[mi][ni][0]); o.y = f2bf(acc[mi][ni][1]);
        o.z = f2bf(acc[mi][ni][2]); o.w = f2bf(acc[mi][ni][3]);
        *(ushort4*)(vt + ((size_t)((b*H_ + h)*D_ + dd))*T_ + t0) = o;
      } else {
#pragma unroll
        for (int r = 0; r < 4; ++r) {
          float val = acc[mi][ni][r];
          float partner = __shfl_xor(val, 1);          // value at dd^1 (lane^1)
          float rot = (dd & 1) ? partner : -partner;   // interleaved rotate_half
          float cv = cosT[(t0 + r)*64 + dd], sv = sinT[(t0 + r)*64 + dd];
          float o = val*cv + rot*sv;
          size_t oidx = (((size_t)(b*H_ + h))*T_ + (t0 + r))*D_ + dd;
          // q pre-scale: 1/sqrt(64) * log2(e)  (softmax done in exp2 domain)
          if (which == 0) qb[oidx] = f2bf(o * 0.180336879f);
          else            kb[oidx] = f2bf(o);
        }
      }
    }
  }
}

// ---------------------------------------------------------------- output-projection GEMM, 128x128, 8 waves
// (unchanged from R19-R22 passing kernel)
__global__ __launch_bounds__(512, 4) void k_gemm1(
    const unsigned short* __restrict__ A, const unsigned short* __restrict__ Bw,
    float* __restrict__ outF)
{
  __shared__ __attribute__((aligned(16))) char smem[65536];
  const int tid = threadIdx.x, l = tid & 63, w = tid >> 6;   // w in 0..7
  const int g = l >> 4, c = l & 15;
  const int m0 = blockIdx.x * 128, n0 = blockIdx.y * 128;
  const int wr = w >> 2, wc = w & 3;
  const char* gA = (const char*)A;
  const char* gB = (const char*)Bw;

  int dstP[2]; size_t aoff[2], boff[2];
#pragma unroll
  for (int j = 0; j < 2; ++j) {
    int P = j*8192 + tid*16;                 // [0, 16384)
    int row = P >> 7;                        // 0..127
    int kc = ((P & 127) ^ ((row & 7) << 4)) >> 1;
    dstP[j] = P;
    aoff[j] = ((size_t)(m0 + row) * KDIM + kc) * 2;
    boff[j] = ((size_t)(n0 + row) * KDIM + kc) * 2;
  }

  const int aB = (wr*64 + c) * 128;            // + par + mi*2048 + xt   (4 mi)
  const int bB = 16384 + (wc*32 + c) * 128;    // + par + ni*2048 + xt   (2 ni)
  const int xsw = (c & 7) << 4;

  f32x4 acc[4][2];
#pragma unroll
  for (int i = 0; i < 4; ++i)
#pragma unroll
    for (int j = 0; j < 2; ++j) acc[i][j] = (f32x4){0.f,0.f,0.f,0.f};

#pragma unroll
  for (int j = 0; j < 2; ++j) {
    gld_lds16(gA + aoff[j], smem + dstP[j]);
    gld_lds16(gB + boff[j], smem + 16384 + dstP[j]);
  }

  for (int t = 0; t < 16; ++t) {
    const int par = (t & 1) << 15;           // 0 or 32768
    const int nxt = par ^ 32768;

    __syncthreads();

    if (t + 1 < 16) {
      const size_t ko = (size_t)(t + 1) * 128;   // +64 bf16 along K
#pragma unroll
      for (int j = 0; j < 2; ++j) {
        gld_lds16(gA + aoff[j] + ko, smem + nxt + dstP[j]);
        gld_lds16(gB + boff[j] + ko, smem + nxt + 16384 + dstP[j]);
      }
    }

#pragma unroll
    for (int kk = 0; kk < 2; ++kk) {
      const int xt = (kk*64 + g*16) ^ xsw;
      bf16x8 af[4], bk[2];
#pragma unroll
      for (int ni = 0; ni < 2; ++ni)
        bk[ni] = *(const bf16x8*)(smem + par + bB + ni*2048 + xt);
#pragma unroll
      for (int mi = 0; mi < 4; ++mi)
        af[mi] = *(const bf16x8*)(smem + par + aB + mi*2048 + xt);
      __builtin_amdgcn_s_setprio(1);
#pragma unroll
      for (int mi = 0; mi < 4; ++mi)
#pragma unroll
        for (int ni = 0; ni < 2; ++ni)
          acc[mi][ni] = __builtin_amdgcn_mfma_f32_16x16x32_bf16(af[mi], bk[ni], acc[mi][ni], 0, 0, 0);
      __builtin_amdgcn_s_setprio(0);
    }
  }

#pragma unroll
  for (int mi = 0; mi < 4; ++mi) {
#pragma unroll
    for (int ni = 0; ni < 2; ++ni) {
      const int mrow0 = m0 + wr*64 + mi*16 + g*4;
      const int ncol  = n0 + wc*32 + ni*16 + c;
#pragma unroll
      for (int r = 0; r < 4; ++r)
        outF[(size_t)(mrow0 + r) * 1024 + ncol] = acc[mi][ni][r];
    }
  }
}

// ---------------------------------------------------------------- flash attention
// LDS-traffic-amortized: 8 waves x 32 q-rows = 256-row q-tile per block.
// Rationale (R22 post-mortem): attn is LDS-pipe-THROUGHPUT-bound; the K/V
// fragment reads (16 of ~18 b128/wave/iter) are identical across waves.
// Doubling q-rows/wave keeps K/V reads constant while doubling work ->
// ~1.8x less LDS traffic per unit work. Grid (64 bh, 8 qt) = 512 blocks,
// big tiles first. LDS: KV dbuf 32KB + P 8x4KB = 64KB (2 blocks/CU).
// Per-wave state (R11-proven shape): aq[2][2], st[4][2], po[4][2], ls[2].
__global__ __launch_bounds__(512) void k_attn(
    const unsigned short* __restrict__ qb, const unsigned short* __restrict__ kb,
    const unsigned short* __restrict__ vt, unsigned short* __restrict__ yb)
{
  __shared__ __attribute__((aligned(16))) char smem[65536]; // 2x(K8K+V8K) + P:32K
  const int tid = threadIdx.x, l = tid & 63, w = tid >> 6;  // w in 0..7
  const int g = l >> 4, c = l & 15;
  const int bh = blockIdx.x;                 // x = bh -> XCD locality
  const int qt = 7 - (int)blockIdx.y;        // big tiles first
  const size_t bhO = (size_t)bh * T_ * D_;
  const int pbase = 32768 + w*4096;          // per-wave 4 KB P region
  const int b = bh >> 4, h = bh & 15;

  bf16x8 vones;
#pragma unroll
  for (int i = 0; i < 8; ++i) vones[i] = (short)0x3F80;   // bf16 1.0

  const char* srcK; const char* srcV; int dstP2;
  {
    int P = w*1024 + l*16;                 // [0, 8192)
    int row = P >> 7;
    int Lb = P ^ ((row & 7) << 4);
    int col = (Lb & 127) >> 1;
    dstP2 = P;
    srcK = (const char*)(kb + bhO) + ((size_t)row*D_ + col)*2;   // + kv0*128B
    srcV = (const char*)(vt + bhO) + ((size_t)row*T_ + col)*2;   // + kv0*2B
  }

  const int q0 = qt * 256;
  const int q0w = q0 + w*32;               // this wave's 32 q rows

  bf16x8 aq[2][2];
#pragma unroll
  for (int mi = 0; mi < 2; ++mi)
#pragma unroll
    for (int kc = 0; kc < 2; ++kc)
      aq[mi][kc] = *(const bf16x8*)(qb + bhO + (size_t)(q0w + mi*16 + c)*D_ + kc*32 + g*8);

  f32x4 po[4][2];
  f32x4 ls[2];
  float mrun[2];
#pragma unroll
  for (int nd = 0; nd < 4; ++nd)
#pragma unroll
    for (int mi = 0; mi < 2; ++mi) po[nd][mi] = (f32x4){0.f,0.f,0.f,0.f};
  ls[0] = (f32x4){0.f,0.f,0.f,0.f}; ls[1] = (f32x4){0.f,0.f,0.f,0.f};
  mrun[0] = mrun[1] = -1e30f;

  const int nkt = (q0 + 256) >> 6;         // = 4(qt+1), always >= 4

  // prologue: stage tile 0 -> buf0; drain; barrier
  gld_lds16(srcK, smem + dstP2);
  gld_lds16(srcV, smem + 8192 + dstP2);
  asm volatile("s_waitcnt vmcnt(0)" ::: "memory");
  __builtin_amdgcn_s_barrier();
  __builtin_amdgcn_sched_barrier(0);

  for (int it = 0; it < nkt; ++it) {
    const int kv0 = it * 64;
    const int cur = (it & 1) * 16384;
    const bool staging = (it + 1 < nkt);

    if (staging) {
      const int wb = 16384 - cur;
      gld_lds16(srcK + (size_t)(kv0 + 64) * 128, smem + wb + dstP2);
      gld_lds16(srcV + (size_t)(kv0 + 64) * 2,   smem + wb + 8192 + dstP2);
    }

    if (kv0 < q0w + 32) {
      // ---- S^T = K Q^T  (64 kv x 32 q per wave); K frags shared across mi
      f32x4 st[4][2];
#pragma unroll
      for (int ni = 0; ni < 4; ++ni)
#pragma unroll
        for (int mi = 0; mi < 2; ++mi) st[ni][mi] = (f32x4){0.f,0.f,0.f,0.f};
      __builtin_amdgcn_s_setprio(1);
#pragma unroll
      for (int kk = 0; kk < 2; ++kk) {
        bf16x8 bk[4];
#pragma unroll
        for (int ni = 0; ni < 4; ++ni) {
          int kn = ni*16 + c;
          int Lb = kn*128 + (kk*32 + g*8)*2;
          bk[ni] = *(const bf16x8*)(smem + cur + (Lb ^ ((kn & 7) << 4)));
        }
#pragma unroll
        for (int ni = 0; ni < 4; ++ni)
#pragma unroll
          for (int mi = 0; mi < 2; ++mi)
            st[ni][mi] = __builtin_amdgcn_mfma_f32_16x16x32_bf16(bk[ni], aq[mi][kk], st[ni][mi], 0, 0, 0);
      }
      __builtin_amdgcn_s_setprio(0);

      // ---- causal mask (partial tiles only)
      if (kv0 + 64 > q0w) {
#pragma unroll
        for (int ni = 0; ni < 4; ++ni)
#pragma unroll
          for (int r = 0; r < 4; ++r) {
            int kvv = kv0 + ni*16 + g*4 + r;
#pragma unroll
            for (int mi = 0; mi < 2; ++mi) {
              int qq = q0w + mi*16 + c;
              if (kvv > qq) st[ni][mi][r] = -1e30f;
            }
          }
      }

      // ---- online softmax per mi (tree max + defer-max; sum via ones-MFMA)
#pragma unroll
      for (int mi = 0; mi < 2; ++mi) {
        float mn[4];
#pragma unroll
        for (int ni = 0; ni < 4; ++ni)
          mn[ni] = fmaxf(fmaxf(st[ni][mi][0], st[ni][mi][1]),
                         fmaxf(st[ni][mi][2], st[ni][mi][3]));
        float mt = fmaxf(fmaxf(mn[0], mn[1]), fmaxf(mn[2], mn[3]));
        mt = fmaxf(mt, __shfl_xor(mt, 16));
        mt = fmaxf(mt, __shfl_xor(mt, 32));
        float m_use = mrun[mi];
        if (__any(mt > m_use + 8.f)) {
          float mnew = fmaxf(m_use, mt);
          float alpha = exp2_fast(m_use - mnew);
          mrun[mi] = mnew;
          m_use = mnew;
#pragma unroll
          for (int r = 0; r < 4; ++r) ls[mi][r] *= alpha;
#pragma unroll
          for (int nd = 0; nd < 4; ++nd)
#pragma unroll
            for (int r = 0; r < 4; ++r) po[nd][mi][r] *= alpha;
        }
#pragma unroll
        for (int ni = 0; ni < 4; ++ni)
#pragma unroll
          for (int r = 0; r < 4; ++r)
            st[ni][mi][r] = exp2_fast(st[ni][mi][r] - m_use);
      }

      // ---- P^T -> LDS (wave-private 4 KB; row = mi*16 + c, col = kv)
#pragma unroll
      for (int mi = 0; mi < 2; ++mi) {
        const int row = mi*16 + c;
        const int sw = (row & 7) << 4;
        const int rb = pbase + row*128;
#pragma unroll
        for (int ni = 0; ni < 4; ++ni) {
          unsigned u0, u1;
          asm("v_cvt_pk_bf16_f32 %0, %1, %2" : "=v"(u0) : "v"(st[ni][mi][0]), "v"(st[ni][mi][1]));
          asm("v_cvt_pk_bf16_f32 %0, %1, %2" : "=v"(u1) : "v"(st[ni][mi][2]), "v"(st[ni][mi][3]));
          int Lb = (ni*16 + g*4) * 2;
          uint2 uu; uu.x = u0; uu.y = u1;
          *(uint2*)(smem + rb + (Lb ^ sw)) = uu;
        }
      }

      // ---- O^T += Vt * P^T ; row-sums via ones-MFMA; V frags shared across mi
      __builtin_amdgcn_s_setprio(1);
#pragma unroll
      for (int kk = 0; kk < 2; ++kk) {
        bf16x8 pb[2];
#pragma unroll
        for (int mi = 0; mi < 2; ++mi) {
          int pr = mi*16 + c;
          int Lb = pr*128 + (kk*32 + g*8)*2;
          pb[mi] = *(const bf16x8*)(smem + pbase + (Lb ^ ((pr & 7) << 4)));
        }
#pragma unroll
        for (int mi = 0; mi < 2; ++mi)
          ls[mi] = __builtin_amdgcn_mfma_f32_16x16x32_bf16(vones, pb[mi], ls[mi], 0, 0, 0);
        bf16x8 bv[4];
#pragma unroll
        for (int nd = 0; nd < 4; ++nd) {
          int vr = nd*16 + c;
          int Lb = vr*128 + (kk*32 + g*8)*2;
          bv[nd] = *(const bf16x8*)(smem + cur + 8192 + (Lb ^ ((vr & 7) << 4)));
        }
#pragma unroll
        for (int nd = 0; nd < 4; ++nd)
#pragma unroll
          for (int mi = 0; mi < 2; ++mi)
            po[nd][mi] = __builtin_amdgcn_mfma_f32_16x16x32_bf16(bv[nd], pb[mi], po[nd][mi], 0, 0, 0);
      }
      __builtin_amdgcn_s_setprio(0);
    }

    if (staging) { asm volatile("s_waitcnt vmcnt(0)" ::: "memory"); }
    __builtin_amdgcn_s_barrier();
    __builtin_amdgcn_sched_barrier(0);
  }

  // ---- normalize + store; ls[mi][0] = full 64-kv sum for q col (mi*16+c)
#pragma unroll
  for (int mi = 0; mi < 2; ++mi) {
    float inv = 1.f / ls[mi][0];
    int t = q0w + mi*16 + c;
#pragma unroll
    for (int nd = 0; nd < 4; ++nd) {
      ushort4 o;
      o.x = f2bf(po[nd][mi][0] * inv);
      o.y = f2bf(po[nd][mi][1] * inv);
      o.z = f2bf(po[nd][mi][2] * inv);
      o.w = f2bf(po[nd][mi][3] * inv);
      *(ushort4*)(yb + ((size_t)b*T_ + t)*C_ + h*64 + nd*16 + g*4) = o;
    }
  }
}

// ---------------------------------------------------------------- launcher
extern "C" void kernel_launch(void* const* d_in, const int* in_sizes, int n_in,
                              void* d_out, int out_size, void* d_ws, size_t ws_size,
                              hipStream_t stream)
{
  const float* x  = (const float*)d_in[0];
  const float* Wq = (const float*)d_in[1];
  const float* Wk = (const float*)d_in[2];
  const float* Wv = (const float*)d_in[3];
  const float* Wp = (const float*)d_in[4];
  const int*   sp = (const int*)d_in[5];
  float* out = (float*)d_out;

  char* ws = (char*)d_ws;
  unsigned short* xb   = (unsigned short*)(ws);                  // 16 MB
  unsigned short* wcat = (unsigned short*)(ws + 16777216);       // 6 MB [Wq;Wk;Wv]
  unsigned short* wpb  = (unsigned short*)(ws + 23068672);       // 2 MB
  unsigned short* qb   = (unsigned short*)(ws + 25165824);       // 16 MB (B,H,T,D)
  unsigned short* kb   = (unsigned short*)(ws + 41943040);       // 16 MB (B,H,T,D)
  unsigned short* vt   = (unsigned short*)(ws + 58720256);       // 16 MB (B,H,D,T)
  unsigned short* yb   = (unsigned short*)(ws + 75497472);       // 16 MB (B*T, C)
  float* cosT = (float*)(ws + 92274688);                         // 512 KB [T][D]
  float* sinT = (float*)(ws + 92798976);                         // 512 KB [T][D]

  k_convert<<<dim3(2048), dim3(256), 0, stream>>>(x, Wq, Wk, Wv, Wp, xb, wcat, wpb);
  k_rope_tab<<<dim3(512), dim3(256), 0, stream>>>(sp, cosT, sinT);
  k_gemm256<<<dim3(32, 16), dim3(1024), 0, stream>>>(xb, wcat, qb, kb, vt, cosT, sinT);
  k_attn<<<dim3(64, 8), dim3(512), 0, stream>>>(qb, kb, vt, yb);
  k_gemm1<<<dim3(64, 8), dim3(512), 0, stream>>>(yb, wpb, out);
}

// Round 24
// 160.213 us; speedup vs baseline: 1.0358x; 1.0358x over previous
//
#include <hip/hip_runtime.h>
#include <hip/hip_bf16.h>
#include <stdint.h>

// Problem constants
#define B_  4
#define T_  2048
#define C_  1024
#define H_  16
#define D_  64
#define BT  (B_*T_)     // 8192
#define KDIM 1024

typedef __attribute__((ext_vector_type(8))) short bf16x8;
typedef __attribute__((ext_vector_type(4))) float f32x4;

__device__ __forceinline__ unsigned short f2bf(float f) {
  union { float f; unsigned u; } v; v.f = f;
  unsigned r = v.u + 0x7FFFu + ((v.u >> 16) & 1u);   // RNE
  return (unsigned short)(r >> 16);
}

__device__ __forceinline__ float exp2_fast(float x) {   // raw v_exp_f32 (2^x)
  float r;
  asm("v_exp_f32 %0, %1" : "=v"(r) : "v"(x));
  return r;
}

// async global->LDS, 16B per lane. dest must be wave-uniform base + lane*16 (linear).
__device__ __forceinline__ void gld_lds16(const void* g, void* l) {
  __builtin_amdgcn_global_load_lds(
      (__attribute__((address_space(1))) unsigned int*)(uintptr_t)g,
      (__attribute__((address_space(3))) unsigned int*)(unsigned)(uintptr_t)l,
      16, 0, 0);
}

// ---------------------------------------------------------------- prep kernels
__global__ __launch_bounds__(256) void k_convert(
    const float* __restrict__ x,  const float* __restrict__ wq,
    const float* __restrict__ wk, const float* __restrict__ wv,
    const float* __restrict__ wp,
    unsigned short* __restrict__ xb, unsigned short* __restrict__ wcat,
    unsigned short* __restrict__ wpb)
{
  const int NX = BT*C_/4;       // 2097152 float4s of x
  const int NW = C_*C_/4;       // 262144 per W
  const int TOT = NX + 4*NW;
  for (int i = blockIdx.x*blockDim.x + threadIdx.x; i < TOT; i += gridDim.x*blockDim.x) {
    const float4* src; unsigned short* dst; int idx;
    if (i < NX)                { src = (const float4*)x;  dst = xb;            idx = i; }
    else {
      int j = i - NX;
      if (j < NW)              { src = (const float4*)wq; dst = wcat;          idx = j; }
      else if (j < 2*NW)       { src = (const float4*)wk; dst = wcat + C_*C_;  idx = j - NW; }
      else if (j < 3*NW)       { src = (const float4*)wv; dst = wcat + 2*C_*C_;idx = j - 2*NW; }
      else                     { src = (const float4*)wp; dst = wpb;           idx = j - 3*NW; }
    }
    float4 v = src[idx];
    ushort4 o; o.x = f2bf(v.x); o.y = f2bf(v.y); o.z = f2bf(v.z); o.w = f2bf(v.w);
    *(ushort4*)(dst + (size_t)idx*4) = o;
  }
}

// RoPE tables [T][D] (coalesced epilogue loads).
__global__ __launch_bounds__(256) void k_rope_tab(
    const int* __restrict__ start_pos, float* __restrict__ cosT, float* __restrict__ sinT)
{
  int i = blockIdx.x*blockDim.x + threadIdx.x;   // [0, T_*64)
  if (i >= T_*D_) return;
  int t = i >> 6, j = i & 63;
  float inv = exp2f(-(float)(j & 31) * (13.287712379549449f / 32.0f));
  float ang = (float)(t + start_pos[0]) * inv;
  cosT[i] = cosf(ang);
  sinT[i] = sinf(ang);
}

// ---------------------------------------------------------------- 256x192 16-wave GEMM (QKV + RoPE)
// (unchanged from R20-R23 passing kernel)
__global__ __launch_bounds__(1024, 4) void k_gemm256(
    const unsigned short* __restrict__ A, const unsigned short* __restrict__ Bw,
    unsigned short* __restrict__ qb, unsigned short* __restrict__ kb,
    unsigned short* __restrict__ vt,
    const float* __restrict__ cosT, const float* __restrict__ sinT)
{
  __shared__ __attribute__((aligned(16))) char smem[114688];   // 2 x 57344
  const int tid = threadIdx.x, l = tid & 63, w = tid >> 6;     // w in 0..15
  const int g = l >> 4, c = l & 15;
  const int m0 = blockIdx.x * 256, n0 = blockIdx.y * 192;
  const int wr = w >> 2, wc = w & 3;
  const char* gA = (const char*)A;
  const char* gB = (const char*)Bw;

  int dstA[2]; size_t aoff[2];
#pragma unroll
  for (int j = 0; j < 2; ++j) {
    int P = j*16384 + tid*16;
    int row = P >> 7;                        // 0..255
    int kc = ((P & 127) ^ ((row & 7) << 4)) >> 1;
    dstA[j] = P;
    aoff[j] = ((size_t)(m0 + row) * KDIM + kc) * 2;
  }
  int dstB[2]; size_t boff[2];
#pragma unroll
  for (int j = 0; j < 2; ++j) {
    int P = (j == 0) ? tid*16 : (16384 + tid*16);   // j=1 valid only tid<512
    int row = P >> 7;
    int kc = ((P & 127) ^ ((row & 7) << 4)) >> 1;
    dstB[j] = P;
    boff[j] = ((size_t)(n0 + row) * KDIM + kc) * 2;
  }
  const bool bsec = (tid < 512);

  const int aB = (wr*64 + c) * 128;            // + par + mi*2048 + xt
  const int bB = 32768 + (wc*48 + c) * 128;    // + par + ni*2048 + xt
  const int xsw = (c & 7) << 4;

  f32x4 acc[4][3];
#pragma unroll
  for (int i = 0; i < 4; ++i)
#pragma unroll
    for (int j = 0; j < 3; ++j) acc[i][j] = (f32x4){0.f,0.f,0.f,0.f};

#pragma unroll
  for (int j = 0; j < 2; ++j) gld_lds16(gA + aoff[j], smem + dstA[j]);
  gld_lds16(gB + boff[0], smem + 32768 + dstB[0]);
  if (bsec) gld_lds16(gB + boff[1], smem + 32768 + dstB[1]);

  for (int t = 0; t < 16; ++t) {
    const int par = (t & 1) ? 57344 : 0;
    const int nxt = (t & 1) ? 0 : 57344;

    __syncthreads();

    if (t + 1 < 16) {
      const size_t ko = (size_t)(t + 1) * 128;
#pragma unroll
      for (int j = 0; j < 2; ++j) gld_lds16(gA + aoff[j] + ko, smem + nxt + dstA[j]);
      gld_lds16(gB + boff[0] + ko, smem + nxt + 32768 + dstB[0]);
      if (bsec) gld_lds16(gB + boff[1] + ko, smem + nxt + 32768 + dstB[1]);
    }

#pragma unroll
    for (int kk = 0; kk < 2; ++kk) {
      const int xt = (kk*64 + g*16) ^ xsw;
      bf16x8 af[4], bk[3];
#pragma unroll
      for (int ni = 0; ni < 3; ++ni)
        bk[ni] = *(const bf16x8*)(smem + par + bB + ni*2048 + xt);
#pragma unroll
      for (int mi = 0; mi < 4; ++mi)
        af[mi] = *(const bf16x8*)(smem + par + aB + mi*2048 + xt);
      __builtin_amdgcn_s_setprio(1);
#pragma unroll
      for (int mi = 0; mi < 4; ++mi)
#pragma unroll
        for (int ni = 0; ni < 3; ++ni)
          acc[mi][ni] = __builtin_amdgcn_mfma_f32_16x16x32_bf16(af[mi], bk[ni], acc[mi][ni], 0, 0, 0);
      __builtin_amdgcn_s_setprio(0);
    }
  }

  // epilogue: fused RoPE; C layout: col = lane&15, row = g*4 + r
#pragma unroll
  for (int mi = 0; mi < 4; ++mi) {
#pragma unroll
    for (int ni = 0; ni < 3; ++ni) {
      const int mrow0 = m0 + wr*64 + mi*16 + g*4;
      const int ncol  = n0 + wc*48 + ni*16 + c;
      const int which = ncol >> 10;          // 0=q 1=k 2=v
      const int d = ncol & 1023, h = d >> 6, dd = d & 63;
      const int b = mrow0 >> 11, t0 = mrow0 & 2047;
      if (which == 2) {
        ushort4 o;
        o.x = f2bf(acc[mi][ni][0]); o.y = f2bf(acc[mi][ni][1]);
        o.z = f2bf(acc[mi][ni][2]); o.w = f2bf(acc[mi][ni][3]);
        *(ushort4*)(vt + ((size_t)((b*H_ + h)*D_ + dd))*T_ + t0) = o;
      } else {
#pragma unroll
        for (int r = 0; r < 4; ++r) {
          float val = acc[mi][ni][r];
          float partner = __shfl_xor(val, 1);          // value at dd^1 (lane^1)
          float rot = (dd & 1) ? partner : -partner;   // interleaved rotate_half
          float cv = cosT[(t0 + r)*64 + dd], sv = sinT[(t0 + r)*64 + dd];
          float o = val*cv + rot*sv;
          size_t oidx = (((size_t)(b*H_ + h))*T_ + (t0 + r))*D_ + dd;
          // q pre-scale: 1/sqrt(64) * log2(e)  (softmax done in exp2 domain)
          if (which == 0) qb[oidx] = f2bf(o * 0.180336879f);
          else            kb[oidx] = f2bf(o);
        }
      }
    }
  }
}

// ---------------------------------------------------------------- output-projection GEMM, 256x128, 16 waves
// Ported to the R17/R20-proven 16-wave recipe: BM=256, BN=128, BK=64,
// 16 waves (4M x 4N), wave tile 64x32 -> acc[4][2] = 32 AGPR (~90 regs ->
// 4 waves/SIMD). LDS 96KB dbuf: parity p at p*49152: [A 32KB | B 16KB],
// proven [rows][128B] layout, byte = row*128 + (kc*2 ^ ((row&7)<<4)).
// Grid (32,8) = 256 blocks = EXACTLY 1 round on 256 CUs (zero tail).
// Staging: A = 2 loads/thread, B = 1 load/thread. 1-barrier/tile schedule.
__global__ __launch_bounds__(1024, 4) void k_gemm1(
    const unsigned short* __restrict__ A, const unsigned short* __restrict__ Bw,
    float* __restrict__ outF)
{
  __shared__ __attribute__((aligned(16))) char smem[98304];   // 2 x 49152
  const int tid = threadIdx.x, l = tid & 63, w = tid >> 6;    // w in 0..15
  const int g = l >> 4, c = l & 15;
  const int m0 = blockIdx.x * 256, n0 = blockIdx.y * 128;
  const int wr = w >> 2, wc = w & 3;
  const char* gA = (const char*)A;
  const char* gB = (const char*)Bw;

  // A staging: 32KB = 2048 chunks, 2/thread; B: 16KB = 1024 chunks, 1/thread
  int dstA[2]; size_t aoff[2];
#pragma unroll
  for (int j = 0; j < 2; ++j) {
    int P = j*16384 + tid*16;
    int row = P >> 7;                        // 0..255
    int kc = ((P & 127) ^ ((row & 7) << 4)) >> 1;
    dstA[j] = P;
    aoff[j] = ((size_t)(m0 + row) * KDIM + kc) * 2;
  }
  int dstB; size_t boff;
  {
    int P = tid*16;                          // [0, 16384)
    int row = P >> 7;                        // 0..127
    int kc = ((P & 127) ^ ((row & 7) << 4)) >> 1;
    dstB = P;
    boff = ((size_t)(n0 + row) * KDIM + kc) * 2;
  }

  const int aB = (wr*64 + c) * 128;            // + par + mi*2048 + xt   (4 mi)
  const int bB = 32768 + (wc*32 + c) * 128;    // + par + ni*2048 + xt   (2 ni)
  const int xsw = (c & 7) << 4;

  f32x4 acc[4][2];
#pragma unroll
  for (int i = 0; i < 4; ++i)
#pragma unroll
    for (int j = 0; j < 2; ++j) acc[i][j] = (f32x4){0.f,0.f,0.f,0.f};

  // prologue: stage tile 0 into parity 0
#pragma unroll
  for (int j = 0; j < 2; ++j) gld_lds16(gA + aoff[j], smem + dstA[j]);
  gld_lds16(gB + boff, smem + 32768 + dstB);

  for (int t = 0; t < 16; ++t) {
    const int par = (t & 1) ? 49152 : 0;
    const int nxt = (t & 1) ? 0 : 49152;

    __syncthreads();

    if (t + 1 < 16) {
      const size_t ko = (size_t)(t + 1) * 128;
#pragma unroll
      for (int j = 0; j < 2; ++j) gld_lds16(gA + aoff[j] + ko, smem + nxt + dstA[j]);
      gld_lds16(gB + boff + ko, smem + nxt + 32768 + dstB);
    }

#pragma unroll
    for (int kk = 0; kk < 2; ++kk) {
      const int xt = (kk*64 + g*16) ^ xsw;
      bf16x8 af[4], bk[2];
#pragma unroll
      for (int ni = 0; ni < 2; ++ni)
        bk[ni] = *(const bf16x8*)(smem + par + bB + ni*2048 + xt);
#pragma unroll
      for (int mi = 0; mi < 4; ++mi)
        af[mi] = *(const bf16x8*)(smem + par + aB + mi*2048 + xt);
      __builtin_amdgcn_s_setprio(1);
#pragma unroll
      for (int mi = 0; mi < 4; ++mi)
#pragma unroll
        for (int ni = 0; ni < 2; ++ni)
          acc[mi][ni] = __builtin_amdgcn_mfma_f32_16x16x32_bf16(af[mi], bk[ni], acc[mi][ni], 0, 0, 0);
      __builtin_amdgcn_s_setprio(0);
    }
  }

  // epilogue: f32 store; C layout: col = lane&15, row = g*4 + r
#pragma unroll
  for (int mi = 0; mi < 4; ++mi) {
#pragma unroll
    for (int ni = 0; ni < 2; ++ni) {
      const int mrow0 = m0 + wr*64 + mi*16 + g*4;
      const int ncol  = n0 + wc*32 + ni*16 + c;
#pragma unroll
      for (int r = 0; r < 4; ++r)
        outF[(size_t)(mrow0 + r) * 1024 + ncol] = acc[mi][ni][r];
    }
  }
}

// ---------------------------------------------------------------- flash attention
// REVERTED to the R21-best kernel (161.0 us total): paired grid (64 bh, 8 p),
// two q-tiles {15-p, p} per block, 8 waves x 16 q-rows, 2-deep KV buffering,
// LDS 48KB, XCD-locality grid, tree-max + ones-MFMA sum + exp2 + defer-max.
__global__ __launch_bounds__(512) void k_attn(
    const unsigned short* __restrict__ qb, const unsigned short* __restrict__ kb,
    const unsigned short* __restrict__ vt, unsigned short* __restrict__ yb)
{
  __shared__ __attribute__((aligned(16))) char smem[49152]; // 2x(K8K+V8K) + P:16K
  const int tid = threadIdx.x, l = tid & 63, w = tid >> 6;  // w in 0..7
  const int g = l >> 4, c = l & 15;
  const int bh = blockIdx.x;                 // x = bh -> XCD locality
  const int pidx = blockIdx.y;               // pair index 0..7
  const size_t bhO = (size_t)bh * T_ * D_;
  const int pbase = 32768 + w*2048;          // per-wave 2 KB P region
  const int b = bh >> 4, h = bh & 15;

  bf16x8 vones;
#pragma unroll
  for (int i = 0; i < 8; ++i) vones[i] = (short)0x3F80;   // bf16 1.0

  const char* srcK; const char* srcV; int dstP2;
  {
    int P = w*1024 + l*16;                 // [0, 8192)
    int row = P >> 7;
    int Lb = P ^ ((row & 7) << 4);
    int col = (Lb & 127) >> 1;
    dstP2 = P;
    srcK = (const char*)(kb + bhO) + ((size_t)row*D_ + col)*2;   // + kv0*128B
    srcV = (const char*)(vt + bhO) + ((size_t)row*T_ + col)*2;   // + kv0*2B
  }

  for (int half = 0; half < 2; ++half) {
    const int qt = half ? pidx : (15 - pidx);
    const int q0 = qt * 128;
    const int q0w = q0 + w*16;             // this wave's 16 q rows

    bf16x8 aq[2];
#pragma unroll
    for (int kc = 0; kc < 2; ++kc)
      aq[kc] = *(const bf16x8*)(qb + bhO + (size_t)(q0w + c)*D_ + kc*32 + g*8);

    f32x4 po[4];
    f32x4 ls;
    float mrun = -1e30f;
#pragma unroll
    for (int nd = 0; nd < 4; ++nd) po[nd] = (f32x4){0.f,0.f,0.f,0.f};
    ls = (f32x4){0.f,0.f,0.f,0.f};

    const int nkt = (q0 + 128) >> 6;       // = 2(qt+1), always >= 2

    // prologue: stage tile 0 -> buf0; drain; barrier
    gld_lds16(srcK, smem + dstP2);
    gld_lds16(srcV, smem + 8192 + dstP2);
    asm volatile("s_waitcnt vmcnt(0)" ::: "memory");
    __builtin_amdgcn_s_barrier();
    __builtin_amdgcn_sched_barrier(0);

    for (int it = 0; it < nkt; ++it) {
      const int kv0 = it * 64;
      const int cur = (it & 1) * 16384;
      const bool staging = (it + 1 < nkt);

      if (staging) {
        const int wb = 16384 - cur;
        gld_lds16(srcK + (size_t)(kv0 + 64) * 128, smem + wb + dstP2);
        gld_lds16(srcV + (size_t)(kv0 + 64) * 2,   smem + wb + 8192 + dstP2);
      }

      if (kv0 < q0w + 16) {
        f32x4 st[4];
#pragma unroll
        for (int ni = 0; ni < 4; ++ni) st[ni] = (f32x4){0.f,0.f,0.f,0.f};
        __builtin_amdgcn_s_setprio(1);
#pragma unroll
        for (int kk = 0; kk < 2; ++kk) {
          bf16x8 bk[4];
#pragma unroll
          for (int ni = 0; ni < 4; ++ni) {
            int kn = ni*16 + c;
            int Lb = kn*128 + (kk*32 + g*8)*2;
            bk[ni] = *(const bf16x8*)(smem + cur + (Lb ^ ((kn & 7) << 4)));
          }
#pragma unroll
          for (int ni = 0; ni < 4; ++ni)
            st[ni] = __builtin_amdgcn_mfma_f32_16x16x32_bf16(bk[ni], aq[kk], st[ni], 0, 0, 0);
        }
        __builtin_amdgcn_s_setprio(0);

        if (kv0 + 64 > q0w) {
          const int qq = q0w + c;
#pragma unroll
          for (int ni = 0; ni < 4; ++ni)
#pragma unroll
            for (int r = 0; r < 4; ++r) {
              int kvv = kv0 + ni*16 + g*4 + r;
              if (kvv > qq) st[ni][r] = -1e30f;
            }
        }

        {
          float mn[4];
#pragma unroll
          for (int ni = 0; ni < 4; ++ni)
            mn[ni] = fmaxf(fmaxf(st[ni][0], st[ni][1]), fmaxf(st[ni][2], st[ni][3]));
          float mt = fmaxf(fmaxf(mn[0], mn[1]), fmaxf(mn[2], mn[3]));
          mt = fmaxf(mt, __shfl_xor(mt, 16));
          mt = fmaxf(mt, __shfl_xor(mt, 32));
          float m_use = mrun;
          if (__any(mt > m_use + 8.f)) {
            float mnew = fmaxf(m_use, mt);
            float alpha = exp2_fast(m_use - mnew);
            mrun = mnew;
            m_use = mnew;
#pragma unroll
            for (int r = 0; r < 4; ++r) ls[r] *= alpha;
#pragma unroll
            for (int nd = 0; nd < 4; ++nd)
#pragma unroll
              for (int r = 0; r < 4; ++r) po[nd][r] *= alpha;
          }
#pragma unroll
          for (int ni = 0; ni < 4; ++ni)
#pragma unroll
            for (int r = 0; r < 4; ++r)
              st[ni][r] = exp2_fast(st[ni][r] - m_use);
        }

        {
          const int row = c;
          const int sw = (row & 7) << 4;
          const int rb = pbase + row*128;
#pragma unroll
          for (int ni = 0; ni < 4; ++ni) {
            unsigned u0, u1;
            asm("v_cvt_pk_bf16_f32 %0, %1, %2" : "=v"(u0) : "v"(st[ni][0]), "v"(st[ni][1]));
            asm("v_cvt_pk_bf16_f32 %0, %1, %2" : "=v"(u1) : "v"(st[ni][2]), "v"(st[ni][3]));
            int Lb = (ni*16 + g*4) * 2;
            uint2 uu; uu.x = u0; uu.y = u1;
            *(uint2*)(smem + rb + (Lb ^ sw)) = uu;
          }
        }

        __builtin_amdgcn_s_setprio(1);
#pragma unroll
        for (int kk = 0; kk < 2; ++kk) {
          bf16x8 pb;
          {
            int pr = c;
            int Lb = pr*128 + (kk*32 + g*8)*2;
            pb = *(const bf16x8*)(smem + pbase + (Lb ^ ((pr & 7) << 4)));
          }
          ls = __builtin_amdgcn_mfma_f32_16x16x32_bf16(vones, pb, ls, 0, 0, 0);
          bf16x8 bv[4];
#pragma unroll
          for (int nd = 0; nd < 4; ++nd) {
            int vr = nd*16 + c;
            int Lb = vr*128 + (kk*32 + g*8)*2;
            bv[nd] = *(const bf16x8*)(smem + cur + 8192 + (Lb ^ ((vr & 7) << 4)));
          }
#pragma unroll
          for (int nd = 0; nd < 4; ++nd)
            po[nd] = __builtin_amdgcn_mfma_f32_16x16x32_bf16(bv[nd], pb, po[nd], 0, 0, 0);
        }
        __builtin_amdgcn_s_setprio(0);
      }

      if (staging) { asm volatile("s_waitcnt vmcnt(0)" ::: "memory"); }
      __builtin_amdgcn_s_barrier();
      __builtin_amdgcn_sched_barrier(0);
    }

    {
      float inv = 1.f / ls[0];
      int t = q0w + c;
#pragma unroll
      for (int nd = 0; nd < 4; ++nd) {
        ushort4 o;
        o.x = f2bf(po[nd][0] * inv);
        o.y = f2bf(po[nd][1] * inv);
        o.z = f2bf(po[nd][2] * inv);
        o.w = f2bf(po[nd][3] * inv);
        *(ushort4*)(yb + ((size_t)b*T_ + t)*C_ + h*64 + nd*16 + g*4) = o;
      }
    }
  }
}

// ---------------------------------------------------------------- launcher
extern "C" void kernel_launch(void* const* d_in, const int* in_sizes, int n_in,
                              void* d_out, int out_size, void* d_ws, size_t ws_size,
                              hipStream_t stream)
{
  const float* x  = (const float*)d_in[0];
  const float* Wq = (const float*)d_in[1];
  const float* Wk = (const float*)d_in[2];
  const float* Wv = (const float*)d_in[3];
  const float* Wp = (const float*)d_in[4];
  const int*   sp = (const int*)d_in[5];
  float* out = (float*)d_out;

  char* ws = (char*)d_ws;
  unsigned short* xb   = (unsigned short*)(ws);                  // 16 MB
  unsigned short* wcat = (unsigned short*)(ws + 16777216);       // 6 MB [Wq;Wk;Wv]
  unsigned short* wpb  = (unsigned short*)(ws + 23068672);       // 2 MB
  unsigned short* qb   = (unsigned short*)(ws + 25165824);       // 16 MB (B,H,T,D)
  unsigned short* kb   = (unsigned short*)(ws + 41943040);       // 16 MB (B,H,T,D)
  unsigned short* vt   = (unsigned short*)(ws + 58720256);       // 16 MB (B,H,D,T)
  unsigned short* yb   = (unsigned short*)(ws + 75497472);       // 16 MB (B*T, C)
  float* cosT = (float*)(ws + 92274688);                         // 512 KB [T][D]
  float* sinT = (float*)(ws + 92798976);                         // 512 KB [T][D]

  k_convert<<<dim3(2048), dim3(256), 0, stream>>>(x, Wq, Wk, Wv, Wp, xb, wcat, wpb);
  k_rope_tab<<<dim3(512), dim3(256), 0, stream>>>(sp, cosT, sinT);
  k_gemm256<<<dim3(32, 16), dim3(1024), 0, stream>>>(xb, wcat, qb, kb, vt, cosT, sinT);
  k_attn<<<dim3(64, 8), dim3(512), 0, stream>>>(qb, kb, vt, yb);
  k_gemm1<<<dim3(32, 8), dim3(1024), 0, stream>>>(yb, wpb, out);
}

// Round 25
// 158.634 us; speedup vs baseline: 1.0461x; 1.0100x over previous
//
#include <hip/hip_runtime.h>
#include <hip/hip_bf16.h>
#include <stdint.h>

// Problem constants
#define B_  4
#define T_  2048
#define C_  1024
#define H_  16
#define D_  64
#define BT  (B_*T_)     // 8192
#define KDIM 1024

typedef __attribute__((ext_vector_type(8))) short bf16x8;
typedef __attribute__((ext_vector_type(4))) float f32x4;

__device__ __forceinline__ unsigned short f2bf(float f) {
  union { float f; unsigned u; } v; v.f = f;
  unsigned r = v.u + 0x7FFFu + ((v.u >> 16) & 1u);   // RNE
  return (unsigned short)(r >> 16);
}

__device__ __forceinline__ float exp2_fast(float x) {   // raw v_exp_f32 (2^x)
  float r;
  asm("v_exp_f32 %0, %1" : "=v"(r) : "v"(x));
  return r;
}

// async global->LDS, 16B per lane. dest must be wave-uniform base + lane*16 (linear).
__device__ __forceinline__ void gld_lds16(const void* g, void* l) {
  __builtin_amdgcn_global_load_lds(
      (__attribute__((address_space(1))) unsigned int*)(uintptr_t)g,
      (__attribute__((address_space(3))) unsigned int*)(unsigned)(uintptr_t)l,
      16, 0, 0);
}

// ---------------------------------------------------------------- fused prep kernel
// Region-partitioned grid (no per-iteration region dispatch):
//   blocks [0,2048):    x fp32->bf16      (2048*1024 float4 = NX exactly)
//   blocks [2048,3072): W  fp32->bf16     (1024*1024 float4 = 4*NW exactly;
//                       'which' is block-uniform: 262144 % 1024 == 0)
//   blocks [3072,3200): RoPE tables [T][D] (128*1024 = T*64 exactly)
__global__ __launch_bounds__(256) void k_prep(
    const float* __restrict__ x,  const float* __restrict__ wq,
    const float* __restrict__ wk, const float* __restrict__ wv,
    const float* __restrict__ wp, const int* __restrict__ start_pos,
    unsigned short* __restrict__ xb, unsigned short* __restrict__ wcat,
    unsigned short* __restrict__ wpb,
    float* __restrict__ cosT, float* __restrict__ sinT)
{
  const int b = blockIdx.x, tid = threadIdx.x;
  if (b < 2048) {
    const float4* src = (const float4*)x;
    const int base = b*1024 + tid;
#pragma unroll
    for (int k = 0; k < 4; ++k) {
      int idx = base + k*256;
      float4 v = src[idx];
      ushort4 o; o.x = f2bf(v.x); o.y = f2bf(v.y); o.z = f2bf(v.z); o.w = f2bf(v.w);
      *(ushort4*)(xb + (size_t)idx*4) = o;
    }
  } else if (b < 3072) {
    const int jb = (b - 2048)*1024 + tid;
    const int which = jb >> 18;              // block-uniform (1024 | 262144)
    const float4* src;
    unsigned short* dst;
    if (which == 0)      { src = (const float4*)wq; dst = wcat; }
    else if (which == 1) { src = (const float4*)wk; dst = wcat + C_*C_; }
    else if (which == 2) { src = (const float4*)wv; dst = wcat + 2*C_*C_; }
    else                 { src = (const float4*)wp; dst = wpb; }
    const int base = jb & 262143;
#pragma unroll
    for (int k = 0; k < 4; ++k) {
      int idx = base + k*256;
      float4 v = src[idx];
      ushort4 o; o.x = f2bf(v.x); o.y = f2bf(v.y); o.z = f2bf(v.z); o.w = f2bf(v.w);
      *(ushort4*)(dst + (size_t)idx*4) = o;
    }
  } else {
    const int i0 = (b - 3072)*1024 + tid;
    const int sp = start_pos[0];
#pragma unroll
    for (int k = 0; k < 4; ++k) {
      int i = i0 + k*256;
      int t = i >> 6, j = i & 63;
      float inv = exp2f(-(float)(j & 31) * (13.287712379549449f / 32.0f));
      float ang = (float)(t + sp) * inv;
      cosT[i] = cosf(ang);
      sinT[i] = sinf(ang);
    }
  }
}

// ---------------------------------------------------------------- 256x192 16-wave GEMM (QKV + RoPE)
// (unchanged from R20-R24 passing kernel)
__global__ __launch_bounds__(1024, 4) void k_gemm256(
    const unsigned short* __restrict__ A, const unsigned short* __restrict__ Bw,
    unsigned short* __restrict__ qb, unsigned short* __restrict__ kb,
    unsigned short* __restrict__ vt,
    const float* __restrict__ cosT, const float* __restrict__ sinT)
{
  __shared__ __attribute__((aligned(16))) char smem[114688];   // 2 x 57344
  const int tid = threadIdx.x, l = tid & 63, w = tid >> 6;     // w in 0..15
  const int g = l >> 4, c = l & 15;
  const int m0 = blockIdx.x * 256, n0 = blockIdx.y * 192;
  const int wr = w >> 2, wc = w & 3;
  const char* gA = (const char*)A;
  const char* gB = (const char*)Bw;

  int dstA[2]; size_t aoff[2];
#pragma unroll
  for (int j = 0; j < 2; ++j) {
    int P = j*16384 + tid*16;
    int row = P >> 7;                        // 0..255
    int kc = ((P & 127) ^ ((row & 7) << 4)) >> 1;
    dstA[j] = P;
    aoff[j] = ((size_t)(m0 + row) * KDIM + kc) * 2;
  }
  int dstB[2]; size_t boff[2];
#pragma unroll
  for (int j = 0; j < 2; ++j) {
    int P = (j == 0) ? tid*16 : (16384 + tid*16);   // j=1 valid only tid<512
    int row = P >> 7;
    int kc = ((P & 127) ^ ((row & 7) << 4)) >> 1;
    dstB[j] = P;
    boff[j] = ((size_t)(n0 + row) * KDIM + kc) * 2;
  }
  const bool bsec = (tid < 512);

  const int aB = (wr*64 + c) * 128;            // + par + mi*2048 + xt
  const int bB = 32768 + (wc*48 + c) * 128;    // + par + ni*2048 + xt
  const int xsw = (c & 7) << 4;

  f32x4 acc[4][3];
#pragma unroll
  for (int i = 0; i < 4; ++i)
#pragma unroll
    for (int j = 0; j < 3; ++j) acc[i][j] = (f32x4){0.f,0.f,0.f,0.f};

#pragma unroll
  for (int j = 0; j < 2; ++j) gld_lds16(gA + aoff[j], smem + dstA[j]);
  gld_lds16(gB + boff[0], smem + 32768 + dstB[0]);
  if (bsec) gld_lds16(gB + boff[1], smem + 32768 + dstB[1]);

  for (int t = 0; t < 16; ++t) {
    const int par = (t & 1) ? 57344 : 0;
    const int nxt = (t & 1) ? 0 : 57344;

    __syncthreads();

    if (t + 1 < 16) {
      const size_t ko = (size_t)(t + 1) * 128;
#pragma unroll
      for (int j = 0; j < 2; ++j) gld_lds16(gA + aoff[j] + ko, smem + nxt + dstA[j]);
      gld_lds16(gB + boff[0] + ko, smem + nxt + 32768 + dstB[0]);
      if (bsec) gld_lds16(gB + boff[1] + ko, smem + nxt + 32768 + dstB[1]);
    }

#pragma unroll
    for (int kk = 0; kk < 2; ++kk) {
      const int xt = (kk*64 + g*16) ^ xsw;
      bf16x8 af[4], bk[3];
#pragma unroll
      for (int ni = 0; ni < 3; ++ni)
        bk[ni] = *(const bf16x8*)(smem + par + bB + ni*2048 + xt);
#pragma unroll
      for (int mi = 0; mi < 4; ++mi)
        af[mi] = *(const bf16x8*)(smem + par + aB + mi*2048 + xt);
      __builtin_amdgcn_s_setprio(1);
#pragma unroll
      for (int mi = 0; mi < 4; ++mi)
#pragma unroll
        for (int ni = 0; ni < 3; ++ni)
          acc[mi][ni] = __builtin_amdgcn_mfma_f32_16x16x32_bf16(af[mi], bk[ni], acc[mi][ni], 0, 0, 0);
      __builtin_amdgcn_s_setprio(0);
    }
  }

  // epilogue: fused RoPE; C layout: col = lane&15, row = g*4 + r
#pragma unroll
  for (int mi = 0; mi < 4; ++mi) {
#pragma unroll
    for (int ni = 0; ni < 3; ++ni) {
      const int mrow0 = m0 + wr*64 + mi*16 + g*4;
      const int ncol  = n0 + wc*48 + ni*16 + c;
      const int which = ncol >> 10;          // 0=q 1=k 2=v
      const int d = ncol & 1023, h = d >> 6, dd = d & 63;
      const int b = mrow0 >> 11, t0 = mrow0 & 2047;
      if (which == 2) {
        ushort4 o;
        o.x = f2bf(acc[mi][ni][0]); o.y = f2bf(acc[mi][ni][1]);
        o.z = f2bf(acc[mi][ni][2]); o.w = f2bf(acc[mi][ni][3]);
        *(ushort4*)(vt + ((size_t)((b*H_ + h)*D_ + dd))*T_ + t0) = o;
      } else {
#pragma unroll
        for (int r = 0; r < 4; ++r) {
          float val = acc[mi][ni][r];
          float partner = __shfl_xor(val, 1);          // value at dd^1 (lane^1)
          float rot = (dd & 1) ? partner : -partner;   // interleaved rotate_half
          float cv = cosT[(t0 + r)*64 + dd], sv = sinT[(t0 + r)*64 + dd];
          float o = val*cv + rot*sv;
          size_t oidx = (((size_t)(b*H_ + h))*T_ + (t0 + r))*D_ + dd;
          // q pre-scale: 1/sqrt(64) * log2(e)  (softmax done in exp2 domain)
          if (which == 0) qb[oidx] = f2bf(o * 0.180336879f);
          else            kb[oidx] = f2bf(o);
        }
      }
    }
  }
}

// ---------------------------------------------------------------- output-projection GEMM, 256x128, 16 waves
// (unchanged from R24 passing kernel)
__global__ __launch_bounds__(1024, 4) void k_gemm1(
    const unsigned short* __restrict__ A, const unsigned short* __restrict__ Bw,
    float* __restrict__ outF)
{
  __shared__ __attribute__((aligned(16))) char smem[98304];   // 2 x 49152
  const int tid = threadIdx.x, l = tid & 63, w = tid >> 6;    // w in 0..15
  const int g = l >> 4, c = l & 15;
  const int m0 = blockIdx.x * 256, n0 = blockIdx.y * 128;
  const int wr = w >> 2, wc = w & 3;
  const char* gA = (const char*)A;
  const char* gB = (const char*)Bw;

  int dstA[2]; size_t aoff[2];
#pragma unroll
  for (int j = 0; j < 2; ++j) {
    int P = j*16384 + tid*16;
    int row = P >> 7;                        // 0..255
    int kc = ((P & 127) ^ ((row & 7) << 4)) >> 1;
    dstA[j] = P;
    aoff[j] = ((size_t)(m0 + row) * KDIM + kc) * 2;
  }
  int dstB; size_t boff;
  {
    int P = tid*16;                          // [0, 16384)
    int row = P >> 7;                        // 0..127
    int kc = ((P & 127) ^ ((row & 7) << 4)) >> 1;
    dstB = P;
    boff = ((size_t)(n0 + row) * KDIM + kc) * 2;
  }

  const int aB = (wr*64 + c) * 128;            // + par + mi*2048 + xt   (4 mi)
  const int bB = 32768 + (wc*32 + c) * 128;    // + par + ni*2048 + xt   (2 ni)
  const int xsw = (c & 7) << 4;

  f32x4 acc[4][2];
#pragma unroll
  for (int i = 0; i < 4; ++i)
#pragma unroll
    for (int j = 0; j < 2; ++j) acc[i][j] = (f32x4){0.f,0.f,0.f,0.f};

#pragma unroll
  for (int j = 0; j < 2; ++j) gld_lds16(gA + aoff[j], smem + dstA[j]);
  gld_lds16(gB + boff, smem + 32768 + dstB);

  for (int t = 0; t < 16; ++t) {
    const int par = (t & 1) ? 49152 : 0;
    const int nxt = (t & 1) ? 0 : 49152;

    __syncthreads();

    if (t + 1 < 16) {
      const size_t ko = (size_t)(t + 1) * 128;
#pragma unroll
      for (int j = 0; j < 2; ++j) gld_lds16(gA + aoff[j] + ko, smem + nxt + dstA[j]);
      gld_lds16(gB + boff + ko, smem + nxt + 32768 + dstB);
    }

#pragma unroll
    for (int kk = 0; kk < 2; ++kk) {
      const int xt = (kk*64 + g*16) ^ xsw;
      bf16x8 af[4], bk[2];
#pragma unroll
      for (int ni = 0; ni < 2; ++ni)
        bk[ni] = *(const bf16x8*)(smem + par + bB + ni*2048 + xt);
#pragma unroll
      for (int mi = 0; mi < 4; ++mi)
        af[mi] = *(const bf16x8*)(smem + par + aB + mi*2048 + xt);
      __builtin_amdgcn_s_setprio(1);
#pragma unroll
      for (int mi = 0; mi < 4; ++mi)
#pragma unroll
        for (int ni = 0; ni < 2; ++ni)
          acc[mi][ni] = __builtin_amdgcn_mfma_f32_16x16x32_bf16(af[mi], bk[ni], acc[mi][ni], 0, 0, 0);
      __builtin_amdgcn_s_setprio(0);
    }
  }

  // epilogue: f32 store; C layout: col = lane&15, row = g*4 + r
#pragma unroll
  for (int mi = 0; mi < 4; ++mi) {
#pragma unroll
    for (int ni = 0; ni < 2; ++ni) {
      const int mrow0 = m0 + wr*64 + mi*16 + g*4;
      const int ncol  = n0 + wc*32 + ni*16 + c;
#pragma unroll
      for (int r = 0; r < 4; ++r)
        outF[(size_t)(mrow0 + r) * 1024 + ncol] = acc[mi][ni][r];
    }
  }
}

// ---------------------------------------------------------------- flash attention
// (unchanged R21-best kernel)
__global__ __launch_bounds__(512) void k_attn(
    const unsigned short* __restrict__ qb, const unsigned short* __restrict__ kb,
    const unsigned short* __restrict__ vt, unsigned short* __restrict__ yb)
{
  __shared__ __attribute__((aligned(16))) char smem[49152]; // 2x(K8K+V8K) + P:16K
  const int tid = threadIdx.x, l = tid & 63, w = tid >> 6;  // w in 0..7
  const int g = l >> 4, c = l & 15;
  const int bh = blockIdx.x;                 // x = bh -> XCD locality
  const int pidx = blockIdx.y;               // pair index 0..7
  const size_t bhO = (size_t)bh * T_ * D_;
  const int pbase = 32768 + w*2048;          // per-wave 2 KB P region
  const int b = bh >> 4, h = bh & 15;

  bf16x8 vones;
#pragma unroll
  for (int i = 0; i < 8; ++i) vones[i] = (short)0x3F80;   // bf16 1.0

  const char* srcK; const char* srcV; int dstP2;
  {
    int P = w*1024 + l*16;                 // [0, 8192)
    int row = P >> 7;
    int Lb = P ^ ((row & 7) << 4);
    int col = (Lb & 127) >> 1;
    dstP2 = P;
    srcK = (const char*)(kb + bhO) + ((size_t)row*D_ + col)*2;   // + kv0*128B
    srcV = (const char*)(vt + bhO) + ((size_t)row*T_ + col)*2;   // + kv0*2B
  }

  for (int half = 0; half < 2; ++half) {
    const int qt = half ? pidx : (15 - pidx);
    const int q0 = qt * 128;
    const int q0w = q0 + w*16;             // this wave's 16 q rows

    bf16x8 aq[2];
#pragma unroll
    for (int kc = 0; kc < 2; ++kc)
      aq[kc] = *(const bf16x8*)(qb + bhO + (size_t)(q0w + c)*D_ + kc*32 + g*8);

    f32x4 po[4];
    f32x4 ls;
    float mrun = -1e30f;
#pragma unroll
    for (int nd = 0; nd < 4; ++nd) po[nd] = (f32x4){0.f,0.f,0.f,0.f};
    ls = (f32x4){0.f,0.f,0.f,0.f};

    const int nkt = (q0 + 128) >> 6;       // = 2(qt+1), always >= 2

    gld_lds16(srcK, smem + dstP2);
    gld_lds16(srcV, smem + 8192 + dstP2);
    asm volatile("s_waitcnt vmcnt(0)" ::: "memory");
    __builtin_amdgcn_s_barrier();
    __builtin_amdgcn_sched_barrier(0);

    for (int it = 0; it < nkt; ++it) {
      const int kv0 = it * 64;
      const int cur = (it & 1) * 16384;
      const bool staging = (it + 1 < nkt);

      if (staging) {
        const int wb = 16384 - cur;
        gld_lds16(srcK + (size_t)(kv0 + 64) * 128, smem + wb + dstP2);
        gld_lds16(srcV + (size_t)(kv0 + 64) * 2,   smem + wb + 8192 + dstP2);
      }

      if (kv0 < q0w + 16) {
        f32x4 st[4];
#pragma unroll
        for (int ni = 0; ni < 4; ++ni) st[ni] = (f32x4){0.f,0.f,0.f,0.f};
        __builtin_amdgcn_s_setprio(1);
#pragma unroll
        for (int kk = 0; kk < 2; ++kk) {
          bf16x8 bk[4];
#pragma unroll
          for (int ni = 0; ni < 4; ++ni) {
            int kn = ni*16 + c;
            int Lb = kn*128 + (kk*32 + g*8)*2;
            bk[ni] = *(const bf16x8*)(smem + cur + (Lb ^ ((kn & 7) << 4)));
          }
#pragma unroll
          for (int ni = 0; ni < 4; ++ni)
            st[ni] = __builtin_amdgcn_mfma_f32_16x16x32_bf16(bk[ni], aq[kk], st[ni], 0, 0, 0);
        }
        __builtin_amdgcn_s_setprio(0);

        if (kv0 + 64 > q0w) {
          const int qq = q0w + c;
#pragma unroll
          for (int ni = 0; ni < 4; ++ni)
#pragma unroll
            for (int r = 0; r < 4; ++r) {
              int kvv = kv0 + ni*16 + g*4 + r;
              if (kvv > qq) st[ni][r] = -1e30f;
            }
        }

        {
          float mn[4];
#pragma unroll
          for (int ni = 0; ni < 4; ++ni)
            mn[ni] = fmaxf(fmaxf(st[ni][0], st[ni][1]), fmaxf(st[ni][2], st[ni][3]));
          float mt = fmaxf(fmaxf(mn[0], mn[1]), fmaxf(mn[2], mn[3]));
          mt = fmaxf(mt, __shfl_xor(mt, 16));
          mt = fmaxf(mt, __shfl_xor(mt, 32));
          float m_use = mrun;
          if (__any(mt > m_use + 8.f)) {
            float mnew = fmaxf(m_use, mt);
            float alpha = exp2_fast(m_use - mnew);
            mrun = mnew;
            m_use = mnew;
#pragma unroll
            for (int r = 0; r < 4; ++r) ls[r] *= alpha;
#pragma unroll
            for (int nd = 0; nd < 4; ++nd)
#pragma unroll
              for (int r = 0; r < 4; ++r) po[nd][r] *= alpha;
          }
#pragma unroll
          for (int ni = 0; ni < 4; ++ni)
#pragma unroll
            for (int r = 0; r < 4; ++r)
              st[ni][r] = exp2_fast(st[ni][r] - m_use);
        }

        {
          const int row = c;
          const int sw = (row & 7) << 4;
          const int rb = pbase + row*128;
#pragma unroll
          for (int ni = 0; ni < 4; ++ni) {
            unsigned u0, u1;
            asm("v_cvt_pk_bf16_f32 %0, %1, %2" : "=v"(u0) : "v"(st[ni][0]), "v"(st[ni][1]));
            asm("v_cvt_pk_bf16_f32 %0, %1, %2" : "=v"(u1) : "v"(st[ni][2]), "v"(st[ni][3]));
            int Lb = (ni*16 + g*4) * 2;
            uint2 uu; uu.x = u0; uu.y = u1;
            *(uint2*)(smem + rb + (Lb ^ sw)) = uu;
          }
        }

        __builtin_amdgcn_s_setprio(1);
#pragma unroll
        for (int kk = 0; kk < 2; ++kk) {
          bf16x8 pb;
          {
            int pr = c;
            int Lb = pr*128 + (kk*32 + g*8)*2;
            pb = *(const bf16x8*)(smem + pbase + (Lb ^ ((pr & 7) << 4)));
          }
          ls = __builtin_amdgcn_mfma_f32_16x16x32_bf16(vones, pb, ls, 0, 0, 0);
          bf16x8 bv[4];
#pragma unroll
          for (int nd = 0; nd < 4; ++nd) {
            int vr = nd*16 + c;
            int Lb = vr*128 + (kk*32 + g*8)*2;
            bv[nd] = *(const bf16x8*)(smem + cur + 8192 + (Lb ^ ((vr & 7) << 4)));
          }
#pragma unroll
          for (int nd = 0; nd < 4; ++nd)
            po[nd] = __builtin_amdgcn_mfma_f32_16x16x32_bf16(bv[nd], pb, po[nd], 0, 0, 0);
        }
        __builtin_amdgcn_s_setprio(0);
      }

      if (staging) { asm volatile("s_waitcnt vmcnt(0)" ::: "memory"); }
      __builtin_amdgcn_s_barrier();
      __builtin_amdgcn_sched_barrier(0);
    }

    {
      float inv = 1.f / ls[0];
      int t = q0w + c;
#pragma unroll
      for (int nd = 0; nd < 4; ++nd) {
        ushort4 o;
        o.x = f2bf(po[nd][0] * inv);
        o.y = f2bf(po[nd][1] * inv);
        o.z = f2bf(po[nd][2] * inv);
        o.w = f2bf(po[nd][3] * inv);
        *(ushort4*)(yb + ((size_t)b*T_ + t)*C_ + h*64 + nd*16 + g*4) = o;
      }
    }
  }
}

// ---------------------------------------------------------------- launcher
extern "C" void kernel_launch(void* const* d_in, const int* in_sizes, int n_in,
                              void* d_out, int out_size, void* d_ws, size_t ws_size,
                              hipStream_t stream)
{
  const float* x  = (const float*)d_in[0];
  const float* Wq = (const float*)d_in[1];
  const float* Wk = (const float*)d_in[2];
  const float* Wv = (const float*)d_in[3];
  const float* Wp = (const float*)d_in[4];
  const int*   sp = (const int*)d_in[5];
  float* out = (float*)d_out;

  char* ws = (char*)d_ws;
  unsigned short* xb   = (unsigned short*)(ws);                  // 16 MB
  unsigned short* wcat = (unsigned short*)(ws + 16777216);       // 6 MB [Wq;Wk;Wv]
  unsigned short* wpb  = (unsigned short*)(ws + 23068672);       // 2 MB
  unsigned short* qb   = (unsigned short*)(ws + 25165824);       // 16 MB (B,H,T,D)
  unsigned short* kb   = (unsigned short*)(ws + 41943040);       // 16 MB (B,H,T,D)
  unsigned short* vt   = (unsigned short*)(ws + 58720256);       // 16 MB (B,H,D,T)
  unsigned short* yb   = (unsigned short*)(ws + 75497472);       // 16 MB (B*T, C)
  float* cosT = (float*)(ws + 92274688);                         // 512 KB [T][D]
  float* sinT = (float*)(ws + 92798976);                         // 512 KB [T][D]

  k_prep<<<dim3(3200), dim3(256), 0, stream>>>(x, Wq, Wk, Wv, Wp, sp, xb, wcat, wpb, cosT, sinT);
  k_gemm256<<<dim3(32, 16), dim3(1024), 0, stream>>>(xb, wcat, qb, kb, vt, cosT, sinT);
  k_attn<<<dim3(64, 8), dim3(512), 0, stream>>>(qb, kb, vt, yb);
  k_gemm1<<<dim3(32, 8), dim3(1024), 0, stream>>>(yb, wpb, out);
}